// Round 5
// baseline (23.157 us; speedup 1.0000x reference)
//
#include <hip/hip_runtime.h>
#include <hip/hip_bf16.h>
#include <math.h>

#define NCELL 32
#define P 128
#define C 4
#define KSEL 64
#define THRESH 0.7f
#define NEGV -1e9f

#define FMA4(acc, av, bv)                                                     \
  acc.x += av.x * bv.x; acc.y += av.y * bv.y;                                 \
  acc.z += av.z * bv.z; acc.w += av.w * bv.w

__device__ __forceinline__ float hsum4(float4 v) {
  return (v.x + v.y) + (v.z + v.w);
}

__global__ __launch_bounds__(256) void pillar_attn_sample_kernel(
    const float* __restrict__ pts,      // [NCELL][P][C]
    const void*  __restrict__ maskp,    // [NCELL][P]  (dtype sniffed)
    const float* __restrict__ pos,      // [P][C]
    const float* __restrict__ q_w, const float* __restrict__ q_b,
    const float* __restrict__ k_w, const float* __restrict__ k_b,
    const float* __restrict__ v_w, const float* __restrict__ v_b,
    const float* __restrict__ w_w, const float* __restrict__ w_b,
    float* __restrict__ out)            // [NCELL*KSEL*C] ++ [NCELL*KSEL]
{
  // ---- LDS ----
  __shared__ __align__(16) float sQ[2048];   // q_w  [c][m][i] = [4][4][128]
  __shared__ __align__(16) float sK[2048];   // k_w
  __shared__ __align__(16) float sV[2048];   // v_w
  __shared__ __align__(16) float sWW[512];   // w_w  [n][i] = [4][128]
  __shared__ __align__(16) float sQB[512];   // q_b  [m][i]
  __shared__ __align__(16) float sKB[512];   // k_b
  __shared__ __align__(16) float sVB[512];   // v_b  [n][i]
  __shared__ float sR[400];    // hatKV Gram: [arow 20][brow 20]
  __shared__ float sG[80];     // corrected Gtilde [g 5][mn 16]
  __shared__ float sVS[20];    // rowsums of b-rows (V 0..15, VB 16..19)
  __shared__ float sWU[4];     // sum of w_w over unmasked
  __shared__ float sC[35];     // cubic monomial coeffs (lex order, 5 vars)
  __shared__ float sC2[5];     // t2 coeffs
  __shared__ float wbuf[P];
  __shared__ unsigned long long sBM[2];      // sel ballots
  __shared__ unsigned long long sMM[2];      // mask ballots
  __shared__ int slotp[KSEL];

  const int cell = blockIdx.x;
  const int t = threadIdx.x;

  // ---- mask dtype detection (uniform) ----
  int mkind;
  {
    const unsigned* u = (const unsigned*)maskp;
    bool i32ok = true, f32ok = true;
    #pragma unroll
    for (int k = 0; k < 8; ++k) {
      unsigned v = u[k];
      if (v != 0u && v != 1u) i32ok = false;
      if (v != 0u && v != 0x3f800000u) f32ok = false;
    }
    mkind = (i32ok || f32ok) ? 0 : 1;
  }

  // ---- early global loads ----
  float4 pv4, po4;
  float wb0 = w_b[0];
  bool mv = false;
  if (t < P) {
    pv4 = ((const float4*)pts)[cell * P + t];
    po4 = ((const float4*)pos)[t];
    if (mkind == 0) mv = ((const unsigned*)maskp)[cell * P + t] != 0u;
    else            mv = ((const unsigned char*)maskp)[cell * P + t] != 0;
  }

  // ---- stage weights into LDS (coalesced float4) ----
  {
    const float4* q4 = (const float4*)q_w;
    const float4* k4 = (const float4*)k_w;
    const float4* v4 = (const float4*)v_w;
    float4* sQ4 = (float4*)sQ; float4* sK4 = (float4*)sK; float4* sV4 = (float4*)sV;
    sQ4[t] = q4[t]; sQ4[t + 256] = q4[t + 256];
    sK4[t] = k4[t]; sK4[t + 256] = k4[t + 256];
    sV4[t] = v4[t]; sV4[t + 256] = v4[t + 256];
    if (t < 128) {
      ((float4*)sWW)[t] = ((const float4*)w_w)[t];
      ((float4*)sKB)[t] = ((const float4*)k_b)[t];
    } else {
      int u = t - 128;
      ((float4*)sQB)[u] = ((const float4*)q_b)[u];
      ((float4*)sVB)[u] = ((const float4*)v_b)[u];
    }
  }
  if (t < P) {
    unsigned long long mm = __ballot(mv);
    if ((t & 63) == 0) sMM[t >> 6] = mm;
  }
  __syncthreads();   // S0: weights + mask ballots ready

  // ---- dot phase: tiled Gram + corrections + rowsums ----
  // a-rows (K-side, 20): r<16 -> K(c=r>>2, m=r&3); r>=16 -> KB(m=r-16)
  // b-rows (V-side, 20): r<16 -> V(d=r>>2, n=r&3); r>=16 -> VB(n=r-16)
  // q-rows (Q-side, 20): r<16 -> Q(c,m); r>=16 -> QB(m)
  {
    const unsigned long long um0 = ~sMM[0];
    const unsigned long long um1 = ~sMM[1];
    const int rot = t & 31;
    if (t < 100) {
      // hatKV 2x2 tile
      int ta = (t / 10) * 2, tb = (t % 10) * 2;
      const float* a0p = (ta < 16) ? sK + (ta >> 2) * 512 + (ta & 3) * 128 : sKB + (ta - 16) * 128;
      int ta1 = ta + 1;
      const float* a1p = (ta1 < 16) ? sK + (ta1 >> 2) * 512 + (ta1 & 3) * 128 : sKB + (ta1 - 16) * 128;
      const float* b0p = (tb < 16) ? sV + (tb >> 2) * 512 + (tb & 3) * 128 : sVB + (tb - 16) * 128;
      int tb1 = tb + 1;
      const float* b1p = (tb1 < 16) ? sV + (tb1 >> 2) * 512 + (tb1 & 3) * 128 : sVB + (tb1 - 16) * 128;
      const float4* a0 = (const float4*)a0p; const float4* a1 = (const float4*)a1p;
      const float4* b0 = (const float4*)b0p; const float4* b1 = (const float4*)b1p;
      float4 z = {0.f,0.f,0.f,0.f};
      float4 c00 = z, c01 = z, c10 = z, c11 = z;
      #pragma unroll
      for (int kk = 0; kk < 32; ++kk) {
        int k = (kk + rot) & 31;
        float4 av0 = a0[k], av1 = a1[k], bv0 = b0[k], bv1 = b1[k];
        FMA4(c00, av0, bv0); FMA4(c01, av0, bv1);
        FMA4(c10, av1, bv0); FMA4(c11, av1, bv1);
      }
      sR[ta * 20 + tb]       = hsum4(c00);
      sR[ta * 20 + tb + 1]   = hsum4(c01);
      sR[ta1 * 20 + tb]      = hsum4(c10);
      sR[ta1 * 20 + tb + 1]  = hsum4(c11);
    } else if (t < 120) {
      // Gtilde 2x2 tile: q-rows x WW rows, masked = full - unmasked correction
      int tile = t - 100;
      int ra = (tile >> 1) * 2, nb = (tile & 1) * 2;
      const float* a0p = (ra < 16) ? sQ + (ra >> 2) * 512 + (ra & 3) * 128 : sQB + (ra - 16) * 128;
      int ra1 = ra + 1;
      const float* a1p = (ra1 < 16) ? sQ + (ra1 >> 2) * 512 + (ra1 & 3) * 128 : sQB + (ra1 - 16) * 128;
      const float* w0p = sWW + nb * 128;
      const float* w1p = sWW + (nb + 1) * 128;
      const float4* a0 = (const float4*)a0p; const float4* a1 = (const float4*)a1p;
      const float4* b0 = (const float4*)w0p; const float4* b1 = (const float4*)w1p;
      float4 z = {0.f,0.f,0.f,0.f};
      float4 c00 = z, c01 = z, c10 = z, c11 = z;
      #pragma unroll
      for (int kk = 0; kk < 32; ++kk) {
        int k = (kk + rot) & 31;
        float4 av0 = a0[k], av1 = a1[k], bv0 = b0[k], bv1 = b1[k];
        FMA4(c00, av0, bv0); FMA4(c01, av0, bv1);
        FMA4(c10, av1, bv0); FMA4(c11, av1, bv1);
      }
      float f00 = hsum4(c00), f01 = hsum4(c01), f10 = hsum4(c10), f11 = hsum4(c11);
      float u00 = 0.f, u01 = 0.f, u10 = 0.f, u11 = 0.f;
      unsigned long long u = um0;
      while (u) {
        int i = __builtin_ctzll(u); u &= u - 1;
        float w0v = w0p[i], w1v = w1p[i], a0v = a0p[i], a1v = a1p[i];
        u00 += a0v * w0v; u01 += a0v * w1v; u10 += a1v * w0v; u11 += a1v * w1v;
      }
      u = um1;
      while (u) {
        int i = __builtin_ctzll(u) + 64; u &= u - 1;
        float w0v = w0p[i], w1v = w1p[i], a0v = a0p[i], a1v = a1p[i];
        u00 += a0v * w0v; u01 += a0v * w1v; u10 += a1v * w0v; u11 += a1v * w1v;
      }
      int g0 = (ra < 16) ? (ra >> 2) : 4,  m0 = (ra < 16) ? (ra & 3) : (ra - 16);
      int g1 = (ra1 < 16) ? (ra1 >> 2) : 4, m1 = (ra1 < 16) ? (ra1 & 3) : (ra1 - 16);
      sG[g0 * 16 + m0 * 4 + nb]     = f00 - u00;
      sG[g0 * 16 + m0 * 4 + nb + 1] = f01 - u01;
      sG[g1 * 16 + m1 * 4 + nb]     = f10 - u10;
      sG[g1 * 16 + m1 * 4 + nb + 1] = f11 - u11;
    } else if (t < 130) {
      // rowsums of b-rows, 2 per thread
      int r0 = (t - 120) * 2;
      #pragma unroll
      for (int rr = 0; rr < 2; ++rr) {
        int r = r0 + rr;
        const float* bp = (r < 16) ? sV + (r >> 2) * 512 + (r & 3) * 128 : sVB + (r - 16) * 128;
        const float4* b4 = (const float4*)bp;
        float4 z = {0.f,0.f,0.f,0.f};
        float4 acc = z;
        #pragma unroll
        for (int kk = 0; kk < 32; ++kk) {
          int k = (kk + rot) & 31;
          float4 bv = b4[k];
          acc.x += bv.x; acc.y += bv.y; acc.z += bv.z; acc.w += bv.w;
        }
        sVS[r] = hsum4(acc);
      }
    } else if (t < 134) {
      // WU[n] = sum of w_w[n] over unmasked
      int n = t - 130;
      const float* wp = sWW + n * 128;
      float s = 0.f;
      unsigned long long u = um0;
      while (u) { int i = __builtin_ctzll(u); u &= u - 1; s += wp[i]; }
      u = um1;
      while (u) { int i = __builtin_ctzll(u) + 64; u &= u - 1; s += wp[i]; }
      sWU[n] = s;
    }
  }
  __syncthreads();   // S2: sR, sG, sVS, sWU ready

  // ---- coefficient phase ----
  if (t < 35) {
    // decode lex monomial index -> (aa<=bb<=cc) over 5 vars
    int aa = 0, bb = 0, cc = 0;
    {
      int idx = 0;
      for (int a = 0; a < 5; ++a)
        for (int b = a; b < 5; ++b)
          for (int c = b; c < 5; ++c) {
            if (idx == t) { aa = a; bb = b; cc = c; }
            ++idx;
          }
    }
    int vals[3] = {aa, bb, cc};
    float coeff = 0.f;
    for (int j = 0; j < 3; ++j) {
      int g = vals[j];
      bool dup = false;
      for (int j2 = 0; j2 < j; ++j2) if (vals[j2] == g) dup = true;
      if (dup) continue;
      int u, v;
      if (j == 0)      { u = bb; v = cc; }
      else if (j == 1) { u = aa; v = cc; }
      else             { u = aa; v = bb; }
      float s = 0.f;
      for (int mm = 0; mm < 4; ++mm) {
        int au  = (u < 4) ? u * 4 + mm : 16 + mm;
        int au2 = (v < 4) ? v * 4 + mm : 16 + mm;
        for (int nn = 0; nn < 4; ++nn) {
          int bv1 = (v < 4) ? v * 4 + nn : 16 + nn;
          float kv = sR[au * 20 + bv1];
          if (u != v) {
            int bv2 = (u < 4) ? u * 4 + nn : 16 + nn;
            kv += sR[au2 * 20 + bv2];
          }
          s += sG[g * 16 + mm * 4 + nn] * kv;
        }
      }
      coeff += s;
    }
    sC[t] = coeff;
  } else if (t < 40) {
    int d = t - 35;
    float s = 0.f;
    if (d < 4) { for (int n = 0; n < 4; ++n) s += sWU[n] * sVS[d * 4 + n]; }
    else       { for (int n = 0; n < 4; ++n) s += sWU[n] * sVS[16 + n]; }
    sC2[d] = s;
  }
  __syncthreads();   // S3: coeffs ready

  // ---- per-point score (35-term cubic + 5-term linear) ----
  bool selp = false;
  if (t < P) {
    const int p = t;
    float xt[5] = {pv4.x + po4.x, pv4.y + po4.y, pv4.z + po4.z, pv4.w + po4.w, 1.f};
    float t1 = 0.f;
    {
      int idx = 0;
      #pragma unroll
      for (int a = 0; a < 5; ++a) {
        float xa = xt[a];
        #pragma unroll
        for (int b = a; b < 5; ++b) {
          float xab = xa * xt[b];
          #pragma unroll
          for (int c = b; c < 5; ++c) {
            t1 += sC[idx] * xab * xt[c];
            ++idx;
          }
        }
      }
    }
    float t2 = sC2[4];
    #pragma unroll
    for (int d = 0; d < 4; ++d) t2 += xt[d] * sC2[d];
    const float scale = 0.0883883476483184f; // 1/sqrt(128)
    float S = t1 * scale + NEGV * t2 + wb0;
    float sig = 1.f / (1.f + expf(-S));
    float wv = mv ? sig : 0.f;
    wbuf[p] = wv;
    selp = (wv > THRESH) && mv;
    unsigned long long bm = __ballot(selp);
    if ((t & 63) == 0) sBM[t >> 6] = bm;
  }
  __syncthreads();   // S4: wbuf + sel ballots ready

  // ---- ranks via ballot popcounts (verified) ----
  int cnt = 0;
  unsigned long long bm0 = sBM[0], bm1 = sBM[1];
  cnt = __builtin_popcountll(bm0) + __builtin_popcountll(bm1);
  if (t < P) {
    const int p = t;
    int rank;
    if (cnt > KSEL) {
      float wp = wbuf[p];
      int rank_top = 0;
      for (int q = 0; q < P; ++q) {
        int sq = (int)((q < 64 ? (bm0 >> q) : (bm1 >> (q - 64))) & 1ull);
        if (sq) {
          float wq = wbuf[q];
          if (wq > wp || (wq == wp && q < p)) ++rank_top;
        }
      }
      rank = rank_top;
    } else {
      rank = (p < 64)
           ? __builtin_popcountll(bm0 & ((1ull << p) - 1ull))
           : __builtin_popcountll(bm0) +
             __builtin_popcountll(bm1 & ((1ull << (p - 64)) - 1ull));
    }
    if (selp && rank < KSEL) slotp[rank] = p;
  }
  __syncthreads();   // S5: slotp ready

  // ---- write outputs (verified) ----
  float* out_pts = out;                       // [NCELL][KSEL][C]
  float* out_w   = out + NCELL * KSEL * C;    // [NCELL][KSEL]
  if (t < KSEL) {
    unsigned long long mm0 = sMM[0], mm1 = sMM[1];
    int fv = mm0 ? __builtin_ctzll(mm0) : (mm1 ? 64 + __builtin_ctzll(mm1) : P);
    int k = t;
    float pw = 0.f;
    float4 pvo = {0.f, 0.f, 0.f, 0.f};
    if (cnt == 0) {
      if (k == 0 && fv < P) {
        pvo = ((const float4*)pts)[cell * P + fv];
        pw = wbuf[fv];
      }
    } else {
      int nval = cnt < KSEL ? cnt : KSEL;
      if (k < nval) {
        int p0 = slotp[k];
        pvo = ((const float4*)pts)[cell * P + p0];
        pw = wbuf[p0];
      }
    }
    ((float4*)out_pts)[cell * KSEL + k] = pvo;
    out_w[cell * KSEL + k] = pw;
  }
}

extern "C" void kernel_launch(void* const* d_in, const int* in_sizes, int n_in,
                              void* d_out, int out_size, void* d_ws, size_t ws_size,
                              hipStream_t stream) {
  const float* pts  = (const float*)d_in[0];
  const void*  msk  = (const void*)d_in[1];
  const float* pos  = (const float*)d_in[2];
  const float* q_w  = (const float*)d_in[3];
  const float* q_b  = (const float*)d_in[4];
  const float* k_w  = (const float*)d_in[5];
  const float* k_b  = (const float*)d_in[6];
  const float* v_w  = (const float*)d_in[7];
  const float* v_b  = (const float*)d_in[8];
  const float* w_w  = (const float*)d_in[9];
  const float* w_b  = (const float*)d_in[10];
  float* out = (float*)d_out;

  pillar_attn_sample_kernel<<<NCELL, 256, 0, stream>>>(
      pts, msk, pos, q_w, q_b, k_w, k_b, v_w, v_b, w_w, w_b, out);
}

// Round 6
// 17.851 us; speedup vs baseline: 1.2972x; 1.2972x over previous
//
#include <hip/hip_runtime.h>
#include <hip/hip_bf16.h>
#include <math.h>

#define NCELL 32
#define P 128
#define C 4
#define KSEL 64
#define THRESH 0.7f
#define NEGV -1e9f

#define FMA4(acc, av, bv)                                                     \
  acc.x += av.x * bv.x; acc.y += av.y * bv.y;                                 \
  acc.z += av.z * bv.z; acc.w += av.w * bv.w

__device__ __forceinline__ float hsum4(float4 v) {
  return (v.x + v.y) + (v.z + v.w);
}

__global__ __launch_bounds__(256) void pillar_attn_sample_kernel(
    const float* __restrict__ pts,      // [NCELL][P][C]
    const void*  __restrict__ maskp,    // [NCELL][P]  (dtype sniffed)
    const float* __restrict__ pos,      // [P][C]
    const float* __restrict__ q_w, const float* __restrict__ q_b,
    const float* __restrict__ k_w, const float* __restrict__ k_b,
    const float* __restrict__ v_w, const float* __restrict__ v_b,
    const float* __restrict__ w_w, const float* __restrict__ w_b,
    float* __restrict__ out)            // [NCELL*KSEL*C] ++ [NCELL*KSEL]
{
  // ---- LDS ----
  __shared__ __align__(16) float sQ[2048];   // q_w  [c][m][i]
  __shared__ __align__(16) float sK[2048];   // k_w
  __shared__ __align__(16) float sV[2048];   // v_w
  __shared__ __align__(16) float sWW[512];   // w_w  [n][i]
  __shared__ __align__(16) float sQB[512];   // q_b  [m][i]
  __shared__ __align__(16) float sKB[512];   // k_b
  __shared__ __align__(16) float sVB[512];   // v_b
  __shared__ __align__(16) float sWM[512];   // masked w_w
  __shared__ __align__(16) float sONE[128];
  __shared__ __align__(16) float sR[400];    // Gram [arow 20][brow 20]
  __shared__ __align__(16) float sG[80];     // Q-side . WM  [qrow 20][n 4]
  __shared__ __align__(16) float sVS[32];    // rowsums: VS 0-15, VBs 16-19, WWs 20-23, WMs 24-27
  __shared__ float sTrash[64];
  __shared__ float wbuf[P];
  __shared__ unsigned long long sBM[2];      // sel ballots
  __shared__ unsigned long long sMM[2];      // mask ballots
  __shared__ int slotp[KSEL];

  const int cell = blockIdx.x;
  const int t = threadIdx.x;

  // ---- mask dtype detection (uniform) ----
  int mkind;
  {
    const unsigned* u = (const unsigned*)maskp;
    bool i32ok = true, f32ok = true;
    #pragma unroll
    for (int k = 0; k < 8; ++k) {
      unsigned v = u[k];
      if (v != 0u && v != 1u) i32ok = false;
      if (v != 0u && v != 0x3f800000u) f32ok = false;
    }
    mkind = (i32ok || f32ok) ? 0 : 1;
  }

  // ---- early global loads ----
  float4 pv4, po4;
  float wb0 = w_b[0];
  bool mv_self;
  {
    int i = t & 127;
    if (mkind == 0) mv_self = ((const unsigned*)maskp)[cell * P + i] != 0u;
    else            mv_self = ((const unsigned char*)maskp)[cell * P + i] != 0;
  }
  const bool mv = mv_self;                   // valid as point-mask for t<128
  if (t < P) {
    pv4 = ((const float4*)pts)[cell * P + t];
    po4 = ((const float4*)pos)[t];
  }

  // ---- stage weights + sWM + mask ballots (all pre-S0, no extra barrier) ----
  {
    const float4* q4 = (const float4*)q_w;
    const float4* k4 = (const float4*)k_w;
    const float4* v4 = (const float4*)v_w;
    float4* sQ4 = (float4*)sQ; float4* sK4 = (float4*)sK; float4* sV4 = (float4*)sV;
    sQ4[t] = q4[t]; sQ4[t + 256] = q4[t + 256];
    sK4[t] = k4[t]; sK4[t + 256] = k4[t + 256];
    sV4[t] = v4[t]; sV4[t + 256] = v4[t + 256];
    if (t < 128) {
      ((float4*)sWW)[t] = ((const float4*)w_w)[t];
      ((float4*)sKB)[t] = ((const float4*)k_b)[t];
    } else {
      int u = t - 128;
      ((float4*)sQB)[u] = ((const float4*)q_b)[u];
      ((float4*)sVB)[u] = ((const float4*)v_b)[u];
      sONE[u] = 1.f;
    }
    // masked w_w from GLOBAL w_w; (t+256)&127 == t&127 so one mask bit serves both
    sWM[t]       = mv_self ? w_w[t]       : 0.f;
    sWM[t + 256] = mv_self ? w_w[t + 256] : 0.f;
  }
  if (t < P) {
    unsigned long long mm = __ballot(mv);
    if ((t & 63) == 0) sMM[t >> 6] = mm;
  }
  __syncthreads();   // S0: weights, sWM, ballots ready

  // ---- dot phase: 134 uniform 2x2-tile units ----
  // K-side rows r: r<16 -> K(r>>2, r&3); r>=16 -> KB(r-16)
  // V-side rows r: r<16 -> V(r>>2, r&3); r>=16 -> VB(r-16)
  // Q-side rows r: r<16 -> Q(r>>2, r&3); r>=16 -> QB(r-16)
  if (t < 134) {
    const float *a0, *a1, *b0, *b1;
    float *o00, *o01, *o10, *o11;
    if (t < 100) {                       // KV Gram tile
      int ta = (t / 10) * 2, tb = (t % 10) * 2;
      int ta1 = ta + 1, tb1 = tb + 1;
      a0 = (ta  < 16) ? sK + (ta  >> 2) * 512 + (ta  & 3) * 128 : sKB + (ta  - 16) * 128;
      a1 = (ta1 < 16) ? sK + (ta1 >> 2) * 512 + (ta1 & 3) * 128 : sKB + (ta1 - 16) * 128;
      b0 = (tb  < 16) ? sV + (tb  >> 2) * 512 + (tb  & 3) * 128 : sVB + (tb  - 16) * 128;
      b1 = (tb1 < 16) ? sV + (tb1 >> 2) * 512 + (tb1 & 3) * 128 : sVB + (tb1 - 16) * 128;
      o00 = &sR[ta * 20 + tb];  o01 = &sR[ta * 20 + tb1];
      o10 = &sR[ta1 * 20 + tb]; o11 = &sR[ta1 * 20 + tb1];
    } else if (t < 120) {                // Q-side x WM tile
      int e = t - 100;
      int ra = (e >> 1) * 2, nb = (e & 1) * 2;
      int ra1 = ra + 1;
      a0 = (ra  < 16) ? sQ + (ra  >> 2) * 512 + (ra  & 3) * 128 : sQB + (ra  - 16) * 128;
      a1 = (ra1 < 16) ? sQ + (ra1 >> 2) * 512 + (ra1 & 3) * 128 : sQB + (ra1 - 16) * 128;
      b0 = sWM + nb * 128; b1 = sWM + (nb + 1) * 128;
      o00 = &sG[ra * 4 + nb];  o01 = &sG[ra * 4 + nb + 1];
      o10 = &sG[ra1 * 4 + nb]; o11 = &sG[ra1 * 4 + nb + 1];
    } else {                             // rowsum pair (b = ones)
      int e = t - 120;
      int r0 = 2 * e, r1 = 2 * e + 1;
      const float* rp0 = (r0 < 16) ? sV + (r0 >> 2) * 512 + (r0 & 3) * 128
                       : (r0 < 20) ? sVB + (r0 - 16) * 128
                       : (r0 < 24) ? sWW + (r0 - 20) * 128
                                   : sWM + (r0 - 24) * 128;
      const float* rp1 = (r1 < 16) ? sV + (r1 >> 2) * 512 + (r1 & 3) * 128
                       : (r1 < 20) ? sVB + (r1 - 16) * 128
                       : (r1 < 24) ? sWW + (r1 - 20) * 128
                                   : sWM + (r1 - 24) * 128;
      a0 = rp0; a1 = rp1; b0 = sONE; b1 = sONE;
      o00 = &sVS[r0]; o01 = &sTrash[e];
      o10 = &sVS[r1]; o11 = &sTrash[32 + e];
    }
    // uniform inner loop (no divergence among active lanes)
    const float4* a04 = (const float4*)a0; const float4* a14 = (const float4*)a1;
    const float4* b04 = (const float4*)b0; const float4* b14 = (const float4*)b1;
    float4 z = {0.f, 0.f, 0.f, 0.f};
    float4 c00 = z, c01 = z, c10 = z, c11 = z;
    const int rot = t & 31;
    #pragma unroll
    for (int kk = 0; kk < 32; ++kk) {
      int k = (kk + rot) & 31;
      float4 av0 = a04[k], av1 = a14[k], bv0 = b04[k], bv1 = b14[k];
      FMA4(c00, av0, bv0); FMA4(c01, av0, bv1);
      FMA4(c10, av1, bv0); FMA4(c11, av1, bv1);
    }
    *o00 = hsum4(c00); *o01 = hsum4(c01);
    *o10 = hsum4(c10); *o11 = hsum4(c11);
  }
  __syncthreads();   // S2: sR, sG, sVS ready

  // ---- per-point score (float4 broadcast LDS reads) ----
  bool selp = false;
  if (t < P) {
    const int p = t;
    float x[C] = {pv4.x + po4.x, pv4.y + po4.y, pv4.z + po4.z, pv4.w + po4.w};
    float xx[C][C];
    #pragma unroll
    for (int c = 0; c < C; ++c)
      #pragma unroll
      for (int d = 0; d < C; ++d) xx[c][d] = x[c] * x[d];

    const float4* sR4 = (const float4*)sR;   // [arow][brow/4]: idx = arow*5 + j
    const float4* sG4 = (const float4*)sG;   // [qrow]: idx = qrow
    const float4* sVS4 = (const float4*)sVS;

    float t1 = 0.f;
    #pragma unroll
    for (int m = 0; m < 4; ++m) {
      float4 A = sG4[16 + m];                        // G0[m][n]
      #pragma unroll
      for (int c = 0; c < C; ++c) {
        float4 gv = sG4[c * 4 + m];                  // G[c][m][n]
        A.x += x[c] * gv.x; A.y += x[c] * gv.y; A.z += x[c] * gv.z; A.w += x[c] * gv.w;
      }
      float4 Bv = sR4[(16 + m) * 5 + 4];             // KB0[m][n]
      #pragma unroll
      for (int c = 0; c < C; ++c) {
        float4 b1v = sR4[(c * 4 + m) * 5 + 4];       // KB1: K(c,m).VB(n)
        float4 b2v = sR4[(16 + m) * 5 + c];          // KB2: KB(m).V(c,n)
        Bv.x += x[c] * (b1v.x + b2v.x); Bv.y += x[c] * (b1v.y + b2v.y);
        Bv.z += x[c] * (b1v.z + b2v.z); Bv.w += x[c] * (b1v.w + b2v.w);
      }
      #pragma unroll
      for (int c = 0; c < C; ++c)
        #pragma unroll
        for (int d = 0; d < C; ++d) {
          float4 kv = sR4[(c * 4 + m) * 5 + d];      // KV: K(c,m).V(d,n)
          float s = xx[c][d];
          Bv.x += s * kv.x; Bv.y += s * kv.y; Bv.z += s * kv.z; Bv.w += s * kv.w;
        }
      t1 += A.x * Bv.x + A.y * Bv.y + A.z * Bv.z + A.w * Bv.w;
    }
    const float scale = 0.0883883476483184f; // 1/sqrt(128)
    float4 WU4, sv4;
    {
      float4 wws = sVS4[5], wms = sVS4[6];
      WU4.x = wws.x - wms.x; WU4.y = wws.y - wms.y;
      WU4.z = wws.z - wms.z; WU4.w = wws.w - wms.w;
      sv4 = sVS4[4];                                 // VBs
      #pragma unroll
      for (int d = 0; d < C; ++d) {
        float4 vs = sVS4[d];                         // VS[d][n]
        sv4.x += x[d] * vs.x; sv4.y += x[d] * vs.y;
        sv4.z += x[d] * vs.z; sv4.w += x[d] * vs.w;
      }
    }
    float t2 = WU4.x * sv4.x + WU4.y * sv4.y + WU4.z * sv4.z + WU4.w * sv4.w;
    float S = t1 * scale + NEGV * t2 + wb0;
    float sig = 1.f / (1.f + expf(-S));
    float wv = mv ? sig : 0.f;
    wbuf[p] = wv;
    selp = (wv > THRESH) && mv;
    unsigned long long bm = __ballot(selp);
    if ((t & 63) == 0) sBM[t >> 6] = bm;
  }
  __syncthreads();   // S3: wbuf + sel ballots ready

  // ---- ranks via ballot popcounts (verified) ----
  int cnt = 0;
  unsigned long long bm0 = sBM[0], bm1 = sBM[1];
  cnt = __builtin_popcountll(bm0) + __builtin_popcountll(bm1);
  if (t < P) {
    const int p = t;
    int rank;
    if (cnt > KSEL) {
      float wp = wbuf[p];
      int rank_top = 0;
      for (int q = 0; q < P; ++q) {
        int sq = (int)((q < 64 ? (bm0 >> q) : (bm1 >> (q - 64))) & 1ull);
        if (sq) {
          float wq = wbuf[q];
          if (wq > wp || (wq == wp && q < p)) ++rank_top;
        }
      }
      rank = rank_top;
    } else {
      rank = (p < 64)
           ? __builtin_popcountll(bm0 & ((1ull << p) - 1ull))
           : __builtin_popcountll(bm0) +
             __builtin_popcountll(bm1 & ((1ull << (p - 64)) - 1ull));
    }
    if (selp && rank < KSEL) slotp[rank] = p;
  }
  __syncthreads();   // S4: slotp ready

  // ---- write outputs (verified) ----
  float* out_pts = out;                       // [NCELL][KSEL][C]
  float* out_w   = out + NCELL * KSEL * C;    // [NCELL][KSEL]
  if (t < KSEL) {
    unsigned long long mm0 = sMM[0], mm1 = sMM[1];
    int fv = mm0 ? __builtin_ctzll(mm0) : (mm1 ? 64 + __builtin_ctzll(mm1) : P);
    int k = t;
    float pw = 0.f;
    float4 pvo = {0.f, 0.f, 0.f, 0.f};
    if (cnt == 0) {
      if (k == 0 && fv < P) {
        pvo = ((const float4*)pts)[cell * P + fv];
        pw = wbuf[fv];
      }
    } else {
      int nval = cnt < KSEL ? cnt : KSEL;
      if (k < nval) {
        int p0 = slotp[k];
        pvo = ((const float4*)pts)[cell * P + p0];
        pw = wbuf[p0];
      }
    }
    ((float4*)out_pts)[cell * KSEL + k] = pvo;
    out_w[cell * KSEL + k] = pw;
  }
}

extern "C" void kernel_launch(void* const* d_in, const int* in_sizes, int n_in,
                              void* d_out, int out_size, void* d_ws, size_t ws_size,
                              hipStream_t stream) {
  const float* pts  = (const float*)d_in[0];
  const void*  msk  = (const void*)d_in[1];
  const float* pos  = (const float*)d_in[2];
  const float* q_w  = (const float*)d_in[3];
  const float* q_b  = (const float*)d_in[4];
  const float* k_w  = (const float*)d_in[5];
  const float* k_b  = (const float*)d_in[6];
  const float* v_w  = (const float*)d_in[7];
  const float* v_b  = (const float*)d_in[8];
  const float* w_w  = (const float*)d_in[9];
  const float* w_b  = (const float*)d_in[10];
  float* out = (float*)d_out;

  pillar_attn_sample_kernel<<<NCELL, 256, 0, stream>>>(
      pts, msk, pos, q_w, q_b, k_w, k_b, v_w, v_b, w_w, w_b, out);
}

// Round 7
// 17.058 us; speedup vs baseline: 1.3575x; 1.0465x over previous
//
#include <hip/hip_runtime.h>
#include <hip/hip_bf16.h>
#include <math.h>

#define NCELL 32
#define P 128
#define C 4
#define KSEL 64
#define THRESH 0.7f
#define NEGV -1e9f

#define FMA4(acc, av, bv)                                                     \
  acc.x += av.x * bv.x; acc.y += av.y * bv.y;                                 \
  acc.z += av.z * bv.z; acc.w += av.w * bv.w

__device__ __forceinline__ float hsum4(float4 v) {
  return (v.x + v.y) + (v.z + v.w);
}

// Physical LDS row map (each row = 128 floats data + 4 pad, stride 132):
//  0..15  K(c,m)   16..19 KB(m)
// 20..35  V(d,n)   36..39 VB(n)
// 40..55  Q(c,m)   56..59 QB(m)
// 60..63  WW(n)    64..67 WM(n)    68 ONES
#define RSTRIDE 132
#define NROWS 69

__global__ __launch_bounds__(256) void pillar_attn_sample_kernel(
    const float* __restrict__ pts,      // [NCELL][P][C]
    const void*  __restrict__ maskp,    // [NCELL][P]  (dtype sniffed)
    const float* __restrict__ pos,      // [P][C]
    const float* __restrict__ q_w, const float* __restrict__ q_b,
    const float* __restrict__ k_w, const float* __restrict__ k_b,
    const float* __restrict__ v_w, const float* __restrict__ v_b,
    const float* __restrict__ w_w, const float* __restrict__ w_b,
    float* __restrict__ out)            // [NCELL*KSEL*C] ++ [NCELL*KSEL]
{
  __shared__ __align__(16) float rowsF[NROWS * RSTRIDE];
  __shared__ __align__(16) float sR[400];    // Gram [Kside 20][Vside 20]
  __shared__ __align__(16) float sG[80];     // [Qside 20][n 4]
  __shared__ __align__(16) float sVS[32];    // VS 0-15, VBs 16-19, WWs 20-23, WMs 24-27
  __shared__ float sTrash[28];
  __shared__ __align__(16) float4 sPts[P];
  __shared__ float wbuf[P];
  __shared__ unsigned long long sBM[2];      // sel ballots
  __shared__ unsigned long long sMM[2];      // mask ballots
  __shared__ int slotp[KSEL];

  const int cell = blockIdx.x;
  const int t = threadIdx.x;

  // ---- mask dtype detection (uniform) ----
  int mkind;
  {
    const unsigned* u = (const unsigned*)maskp;
    bool i32ok = true, f32ok = true;
    #pragma unroll
    for (int k = 0; k < 8; ++k) {
      unsigned v = u[k];
      if (v != 0u && v != 1u) i32ok = false;
      if (v != 0u && v != 0x3f800000u) f32ok = false;
    }
    mkind = (i32ok || f32ok) ? 0 : 1;
  }

  // ---- own mask bit (element t&127) ----
  bool mv_self;
  {
    int i = t & 127;
    if (mkind == 0) mv_self = ((const unsigned*)maskp)[cell * P + i] != 0u;
    else            mv_self = ((const unsigned char*)maskp)[cell * P + i] != 0;
  }
  const bool mv = mv_self;

  // ---- early global loads ----
  float4 pv4, po4;
  float wb0 = w_b[0];
  if (t < P) {
    pv4 = ((const float4*)pts)[cell * P + t];
    po4 = ((const float4*)pos)[t];
  }

  // ---- stage weights into strided row pool (coalesced float4 reads) ----
  {
    const float4* q4  = (const float4*)q_w;
    const float4* k4  = (const float4*)k_w;
    const float4* v4  = (const float4*)v_w;
    #pragma unroll
    for (int rep = 0; rep < 2; ++rep) {
      int g = t + rep * 256;               // 0..511 float4 chunks
      int r = g >> 5, ch = g & 31;
      ((float4*)(rowsF + (0  + r) * RSTRIDE))[ch] = k4[g];   // K rows 0..15
      ((float4*)(rowsF + (20 + r) * RSTRIDE))[ch] = v4[g];   // V rows 20..35
      ((float4*)(rowsF + (40 + r) * RSTRIDE))[ch] = q4[g];   // Q rows 40..55
    }
    if (t < 128) {
      int r = t >> 5, ch = t & 31;
      ((float4*)(rowsF + (16 + r) * RSTRIDE))[ch] = ((const float4*)k_b)[t]; // KB
      ((float4*)(rowsF + (60 + r) * RSTRIDE))[ch] = ((const float4*)w_w)[t]; // WW
    } else {
      int u = t - 128;
      int r = u >> 5, ch = u & 31;
      ((float4*)(rowsF + (36 + r) * RSTRIDE))[ch] = ((const float4*)v_b)[u]; // VB
      ((float4*)(rowsF + (56 + r) * RSTRIDE))[ch] = ((const float4*)q_b)[u]; // QB
    }
    // masked w_w rows 64..67 (scalar; one own mask bit serves both elements)
    rowsF[(64 + (t >> 7)) * RSTRIDE + (t & 127)]       = mv_self ? w_w[t]       : 0.f;
    rowsF[(66 + (t >> 7)) * RSTRIDE + (t & 127)]       = mv_self ? w_w[t + 256] : 0.f;
    if (t < 128) { rowsF[68 * RSTRIDE + t] = 1.f; sPts[t] = pv4; }
  }
  if (t < P) {
    unsigned long long mm = __ballot(mv);
    if ((t & 63) == 0) sMM[t >> 6] = mm;
  }
  __syncthreads();   // S0: rows, sPts, mask ballots ready

  // ---- dot phase: 134 uniform 2x2 tile units, k-uniform reads ----
  if (t < 134) {
    int pa0, pa1, pb0, pb1;
    float *o00, *o01, *o10, *o11;
    if (t < 100) {                       // KV Gram tiles, pairs (u,u+10)x(v,v+10)
      int up = t / 10, vq = t % 10;
      pa0 = up;       pa1 = up + 10;
      pb0 = 20 + vq;  pb1 = 30 + vq;
      o00 = &sR[up * 20 + vq];        o01 = &sR[up * 20 + vq + 10];
      o10 = &sR[(up + 10) * 20 + vq]; o11 = &sR[(up + 10) * 20 + vq + 10];
    } else if (t < 120) {                // Qside x WM tiles
      int e = t - 100;
      int p = e >> 1, nb = (e & 1) * 2;
      pa0 = 40 + p;  pa1 = 50 + p;
      pb0 = 64 + nb; pb1 = 65 + nb;
      o00 = &sG[p * 4 + nb];         o01 = &sG[p * 4 + nb + 1];
      o10 = &sG[(p + 10) * 4 + nb];  o11 = &sG[(p + 10) * 4 + nb + 1];
    } else {                             // rowsums: a = ONES row
      int e = t - 120;                   // 0..13
      int l0 = 2 * e, l1 = 2 * e + 1;
      int r0 = (l0 < 16) ? 20 + l0 : (l0 < 20) ? 36 + (l0 - 16)
             : (l0 < 24) ? 60 + (l0 - 20) : 64 + (l0 - 24);
      int r1 = (l1 < 16) ? 20 + l1 : (l1 < 20) ? 36 + (l1 - 16)
             : (l1 < 24) ? 60 + (l1 - 20) : 64 + (l1 - 24);
      pa0 = 68; pa1 = 68;
      pb0 = r0; pb1 = r1;
      o00 = &sVS[l0]; o01 = &sVS[l1];
      o10 = &sTrash[e]; o11 = &sTrash[e + 14];
    }
    const float4* a0 = (const float4*)(rowsF + pa0 * RSTRIDE);
    const float4* a1 = (const float4*)(rowsF + pa1 * RSTRIDE);
    const float4* b0 = (const float4*)(rowsF + pb0 * RSTRIDE);
    const float4* b1 = (const float4*)(rowsF + pb1 * RSTRIDE);
    float4 z = {0.f, 0.f, 0.f, 0.f};
    float4 c00 = z, c01 = z, c10 = z, c11 = z;
    #pragma unroll
    for (int k = 0; k < 32; ++k) {       // immediate-offset ds_read_b128
      float4 av0 = a0[k], av1 = a1[k], bv0 = b0[k], bv1 = b1[k];
      FMA4(c00, av0, bv0); FMA4(c01, av0, bv1);
      FMA4(c10, av1, bv0); FMA4(c11, av1, bv1);
    }
    *o00 = hsum4(c00); *o01 = hsum4(c01);
    *o10 = hsum4(c10); *o11 = hsum4(c11);
  }
  __syncthreads();   // S2: sR, sG, sVS ready

  // ---- per-point score (verified R6 arithmetic) ----
  bool selp = false;
  if (t < P) {
    const int p = t;
    float x[C] = {pv4.x + po4.x, pv4.y + po4.y, pv4.z + po4.z, pv4.w + po4.w};
    float xx[C][C];
    #pragma unroll
    for (int c = 0; c < C; ++c)
      #pragma unroll
      for (int d = 0; d < C; ++d) xx[c][d] = x[c] * x[d];

    const float4* sR4 = (const float4*)sR;   // [Kside row][Vside/4]: row*5+j
    const float4* sG4 = (const float4*)sG;   // [Qside row]
    const float4* sVS4 = (const float4*)sVS;

    float t1 = 0.f;
    #pragma unroll
    for (int m = 0; m < 4; ++m) {
      float4 A = sG4[16 + m];                        // G0[m][n]
      #pragma unroll
      for (int c = 0; c < C; ++c) {
        float4 gv = sG4[c * 4 + m];                  // G[c][m][n]
        A.x += x[c] * gv.x; A.y += x[c] * gv.y; A.z += x[c] * gv.z; A.w += x[c] * gv.w;
      }
      float4 Bv = sR4[(16 + m) * 5 + 4];             // KB0[m][n]
      #pragma unroll
      for (int c = 0; c < C; ++c) {
        float4 b1v = sR4[(c * 4 + m) * 5 + 4];       // K(c,m).VB(n)
        float4 b2v = sR4[(16 + m) * 5 + c];          // KB(m).V(c,n)
        Bv.x += x[c] * (b1v.x + b2v.x); Bv.y += x[c] * (b1v.y + b2v.y);
        Bv.z += x[c] * (b1v.z + b2v.z); Bv.w += x[c] * (b1v.w + b2v.w);
      }
      #pragma unroll
      for (int c = 0; c < C; ++c)
        #pragma unroll
        for (int d = 0; d < C; ++d) {
          float4 kv = sR4[(c * 4 + m) * 5 + d];      // K(c,m).V(d,n)
          float s = xx[c][d];
          Bv.x += s * kv.x; Bv.y += s * kv.y; Bv.z += s * kv.z; Bv.w += s * kv.w;
        }
      t1 += A.x * Bv.x + A.y * Bv.y + A.z * Bv.z + A.w * Bv.w;
    }
    const float scale = 0.0883883476483184f; // 1/sqrt(128)
    float4 WU4, sv4;
    {
      float4 wws = sVS4[5], wms = sVS4[6];
      WU4.x = wws.x - wms.x; WU4.y = wws.y - wms.y;
      WU4.z = wws.z - wms.z; WU4.w = wws.w - wms.w;
      sv4 = sVS4[4];                                 // VBs
      #pragma unroll
      for (int d = 0; d < C; ++d) {
        float4 vs = sVS4[d];                         // VS[d][n]
        sv4.x += x[d] * vs.x; sv4.y += x[d] * vs.y;
        sv4.z += x[d] * vs.z; sv4.w += x[d] * vs.w;
      }
    }
    float t2 = WU4.x * sv4.x + WU4.y * sv4.y + WU4.z * sv4.z + WU4.w * sv4.w;
    float S = t1 * scale + NEGV * t2 + wb0;
    float sig = 1.f / (1.f + expf(-S));
    float wv = mv ? sig : 0.f;
    wbuf[p] = wv;
    selp = (wv > THRESH) && mv;
    unsigned long long bm = __ballot(selp);
    if ((t & 63) == 0) sBM[t >> 6] = bm;
  }
  __syncthreads();   // S3: wbuf + sel ballots ready

  // ---- selection + write ----
  unsigned long long bm0 = sBM[0], bm1 = sBM[1];
  int cnt = __builtin_popcountll(bm0) + __builtin_popcountll(bm1);
  float* out_pts = out;                       // [NCELL][KSEL][C]
  float* out_w   = out + NCELL * KSEL * C;    // [NCELL][KSEL]

  if (cnt > KSEL) {
    // rare path: weight-descending rank (verified R6 logic)
    if (t < P) {
      const int p = t;
      float wp = wbuf[p];
      int rank_top = 0;
      for (int q = 0; q < P; ++q) {
        int sq = (int)((q < 64 ? (bm0 >> q) : (bm1 >> (q - 64))) & 1ull);
        if (sq) {
          float wq = wbuf[q];
          if (wq > wp || (wq == wp && q < p)) ++rank_top;
        }
      }
      if (selp && rank_top < KSEL) slotp[rank_top] = p;
    }
    __syncthreads();   // S4: slotp ready
    if (t < KSEL) {
      int p0 = slotp[t];
      ((float4*)out_pts)[cell * KSEL + t] = sPts[p0];
      out_w[cell * KSEL + t] = wbuf[p0];
    }
  } else {
    // common path: slot k = k-th set bit (ascending index), no barrier
    if (t < KSEL) {
      unsigned long long mm0 = sMM[0], mm1 = sMM[1];
      int fv = mm0 ? __builtin_ctzll(mm0) : (mm1 ? 64 + __builtin_ctzll(mm1) : P);
      float pw = 0.f;
      float4 pvo = {0.f, 0.f, 0.f, 0.f};
      if (cnt == 0) {
        if (t == 0 && fv < P) { pvo = sPts[fv]; pw = wbuf[fv]; }
      } else if (t < cnt) {
        int pc0 = __builtin_popcountll(bm0);
        unsigned long long w; int base, k;
        if (t < pc0) { w = bm0; base = 0; k = t; }
        else         { w = bm1; base = 64; k = t - pc0; }
        for (; k > 0; --k) w &= w - 1;
        int p0 = base + __builtin_ctzll(w);
        pvo = sPts[p0]; pw = wbuf[p0];
      }
      ((float4*)out_pts)[cell * KSEL + t] = pvo;
      out_w[cell * KSEL + t] = pw;
    }
  }
}

extern "C" void kernel_launch(void* const* d_in, const int* in_sizes, int n_in,
                              void* d_out, int out_size, void* d_ws, size_t ws_size,
                              hipStream_t stream) {
  const float* pts  = (const float*)d_in[0];
  const void*  msk  = (const void*)d_in[1];
  const float* pos  = (const float*)d_in[2];
  const float* q_w  = (const float*)d_in[3];
  const float* q_b  = (const float*)d_in[4];
  const float* k_w  = (const float*)d_in[5];
  const float* k_b  = (const float*)d_in[6];
  const float* v_w  = (const float*)d_in[7];
  const float* v_b  = (const float*)d_in[8];
  const float* w_w  = (const float*)d_in[9];
  const float* w_b  = (const float*)d_in[10];
  float* out = (float*)d_out;

  pillar_attn_sample_kernel<<<NCELL, 256, 0, stream>>>(
      pts, msk, pos, q_w, q_b, k_w, k_b, v_w, v_b, w_w, w_b, out);
}